// Round 3
// baseline (966.028 us; speedup 1.0000x reference)
//
#include <hip/hip_runtime.h>

#define NN 10000
#define NE 640000
#define SLOPE 0.22916666666666666f

__device__ __forceinline__ float blo(unsigned v){ return __uint_as_float(v << 16); }
__device__ __forceinline__ float bhi(unsigned v){ return __uint_as_float(v & 0xffff0000u); }
__device__ __forceinline__ unsigned f2b(float x){
  unsigned u = __float_as_uint(x);
  return (u + 0x7fffu + ((u >> 16) & 1u)) >> 16;
}
__device__ __forceinline__ unsigned pack2(float a, float b){
  return f2b(a) | (f2b(b) << 16);
}
__device__ __forceinline__ float rrelu(float x){ return x >= 0.f ? x : x * SLOPE; }
__device__ __forceinline__ int clampi(int x, int hi){ return x < 0 ? 0 : (x > hi ? hi : x); }

// load/store feature PAIR (2j, 2j+1) of a 128-wide row; i = row*64 + j
__device__ __forceinline__ float2 ld2(const void* p, long i, int f32){
  if (f32) return ((const float2*)p)[i];
  unsigned v = ((const unsigned*)p)[i];
  return make_float2(blo(v), bhi(v));
}
__device__ __forceinline__ void st2(void* p, long i, float2 v, int f32){
  if (f32) ((float2*)p)[i] = v;
  else ((unsigned*)p)[i] = pack2(v.x, v.y);
}

// dtype sniffer: bf16 normal values -> bf16-exponent field in [100,135] for
// ~every u16; f32 data -> low-half u16s have uniform exponent fields (~292/512 pass).
__global__ void k_detect(const unsigned short* __restrict__ w1, int* __restrict__ flag){
  if (blockIdx.x == 0 && threadIdx.x == 0){
    int pass = 0;
    for (int i = 0; i < 512; ++i){
      unsigned short u = w1[i];
      int e = (u >> 7) & 0xFF;
      if ((u & 0x7FFF) == 0 || (e >= 100 && e <= 135)) pass++;
    }
    *flag = (pass < 450) ? 1 : 0;   // 1 => inputs are float32
  }
}

__global__ void k_zero(int* __restrict__ p, int n){
  int i = blockIdx.x * blockDim.x + threadIdx.x;
  if (i < n) p[i] = 0;
}

__global__ void k_hist(const int* __restrict__ dst, int* __restrict__ deg){
  int e = blockIdx.x * blockDim.x + threadIdx.x;
  if (e < NE) atomicAdd(&deg[clampi(dst[e], NN - 1)], 1);
}

__global__ __launch_bounds__(1024) void k_scan(const int* __restrict__ deg,
                                               int* __restrict__ row_ptr,
                                               int* __restrict__ cursor){
  __shared__ int part[1024];
  int t = threadIdx.x;
  int base = t * 10;
  int local[10];
  int s = 0;
  #pragma unroll
  for (int j = 0; j < 10; j++){
    int idx = base + j;
    int v = (idx < NN) ? deg[idx] : 0;
    local[j] = s; s += v;
  }
  part[t] = s;
  __syncthreads();
  for (int off = 1; off < 1024; off <<= 1){
    int v = (t >= off) ? part[t - off] : 0;
    __syncthreads();
    part[t] += v;
    __syncthreads();
  }
  int pre = (t == 0) ? 0 : part[t - 1];
  #pragma unroll
  for (int j = 0; j < 10; j++){
    int idx = base + j;
    if (idx < NN){ int rp = pre + local[j]; row_ptr[idx] = rp; cursor[idx] = rp; }
  }
  if (t == 1023) row_ptr[NN] = part[1023];
}

__global__ void k_scatter(const int* __restrict__ src, const int* __restrict__ dst,
                          int* __restrict__ cursor,
                          int* __restrict__ csr_src, int* __restrict__ csr_eid){
  int e = blockIdx.x * blockDim.x + threadIdx.x;
  if (e >= NE) return;
  int d = clampi(dst[e], NN - 1);
  int p = clampi(atomicAdd(&cursor[d], 1), NE - 1);
  csr_src[p] = clampi(src[e], NN - 1);
  csr_eid[p] = e;
}

__global__ __launch_bounds__(256) void k_edge_agg(const void* __restrict__ ef,
                                                  const int* __restrict__ row_ptr,
                                                  const int* __restrict__ csr_eid,
                                                  unsigned* __restrict__ eagg,
                                                  const int* __restrict__ flag){
  int f32 = *flag;
  int wave = threadIdx.x >> 6, lane = threadIdx.x & 63;
  int n = blockIdx.x * 4 + wave;
  if (n >= NN) return;
  int beg = row_ptr[n], end = row_ptr[n + 1];
  float a0 = 0.f, a1 = 0.f;
  for (int i = beg; i < end; ++i){
    int e = clampi(csr_eid[i], NE - 1);
    float2 v = ld2(ef, (long)e * 64 + lane, f32);
    a0 += v.x; a1 += v.y;
  }
  eagg[n * 64 + lane] = pack2(a0, a1);
}

__global__ __launch_bounds__(256) void k_agg_h(const void* __restrict__ h, int hf32,
                                               const int* __restrict__ row_ptr,
                                               const int* __restrict__ csr_src,
                                               const unsigned* __restrict__ eagg,
                                               const int* __restrict__ deg,
                                               unsigned* __restrict__ A,
                                               const int* __restrict__ flag){
  int f32 = hf32 ? *flag : 0;
  int wave = threadIdx.x >> 6, lane = threadIdx.x & 63;
  int n = blockIdx.x * 4 + wave;
  if (n >= NN) return;
  int beg = row_ptr[n], end = row_ptr[n + 1];
  unsigned ev = eagg[n * 64 + lane];
  float a0 = blo(ev), a1 = bhi(ev);
  for (int i = beg; i < end; ++i){
    int s = clampi(csr_src[i], NN - 1);
    float2 v = ld2(h, (long)s * 64 + lane, f32);
    a0 += v.x; a1 += v.y;
  }
  float inv = 1.f / fmaxf((float)deg[n], 1.f);
  A[n * 64 + lane] = pack2(a0 * inv, a1 * inv);
}

// deg==0 nodes: stash rrelu(h @ W3[layer]) into the A row. woff = pair offset.
__global__ __launch_bounds__(256) void k_iso_pre(const void* __restrict__ H, int hf32,
                                                 const void* __restrict__ W3, long woff,
                                                 const int* __restrict__ deg,
                                                 unsigned* __restrict__ A,
                                                 const int* __restrict__ flag){
  int f32 = *flag;
  int hh = hf32 ? f32 : 0;
  int wave = threadIdx.x >> 6, lane = threadIdx.x & 63;
  int n = blockIdx.x * 4 + wave;
  if (n >= NN) return;
  if (deg[n] != 0) return;
  float a0 = 0.f, a1 = 0.f;
  for (int kk = 0; kk < 64; ++kk){
    float2 hv = ld2(H, (long)n * 64 + kk, hh);
    float2 wa = ld2(W3, woff + (long)(2 * kk) * 64 + lane, f32);
    float2 wb = ld2(W3, woff + (long)(2 * kk + 1) * 64 + lane, f32);
    a0 += hv.x * wa.x + hv.y * wb.x;
    a1 += hv.x * wa.y + hv.y * wb.y;
  }
  A[n * 64 + lane] = pack2(rrelu(a0), rrelu(a1));
}

// out[n] = rrelu(A[n] @ W1[layer] + H[n] @ W2[layer]); in-place safe (own row only)
__global__ __launch_bounds__(256) void k_lin(const unsigned* __restrict__ A,
                                             const void* __restrict__ H, int hf32,
                                             const void* __restrict__ W1,
                                             const void* __restrict__ W2, long woff,
                                             void* __restrict__ out,
                                             const int* __restrict__ flag){
  int f32 = *flag;
  int hh = hf32 ? f32 : 0;
  int wave = threadIdx.x >> 6, lane = threadIdx.x & 63;
  int n = blockIdx.x * 4 + wave;
  if (n >= NN) return;
  float a0 = 0.f, a1 = 0.f;
  for (int kk = 0; kk < 64; ++kk){
    unsigned av = A[n * 64 + kk];
    float A0 = blo(av), A1 = bhi(av);
    float2 hv = ld2(H, (long)n * 64 + kk, hh);
    float2 w1a = ld2(W1, woff + (long)(2 * kk) * 64 + lane, f32);
    float2 w1b = ld2(W1, woff + (long)(2 * kk + 1) * 64 + lane, f32);
    float2 w2a = ld2(W2, woff + (long)(2 * kk) * 64 + lane, f32);
    float2 w2b = ld2(W2, woff + (long)(2 * kk + 1) * 64 + lane, f32);
    a0 += A0 * w1a.x + A1 * w1b.x + hv.x * w2a.x + hv.y * w2b.x;
    a1 += A0 * w1a.y + A1 * w1b.y + hv.x * w2a.y + hv.y * w2b.y;
  }
  st2(out, (long)n * 64 + lane, make_float2(rrelu(a0), rrelu(a1)), f32);
}

__global__ __launch_bounds__(256) void k_iso_post(const unsigned* __restrict__ A,
                                                  const int* __restrict__ deg,
                                                  void* __restrict__ out,
                                                  const int* __restrict__ flag){
  int f32 = *flag;
  int wave = threadIdx.x >> 6, lane = threadIdx.x & 63;
  int n = blockIdx.x * 4 + wave;
  if (n >= NN) return;
  if (deg[n] != 0) return;
  unsigned v = A[n * 64 + lane];
  st2(out, (long)n * 64 + lane, make_float2(blo(v), bhi(v)), f32);
}

extern "C" void kernel_launch(void* const* d_in, const int* in_sizes, int n_in,
                              void* d_out, int out_size, void* d_ws, size_t ws_size,
                              hipStream_t stream) {
  const void* nf  = d_in[0];
  const void* ef  = d_in[1];
  const int*  src = (const int*)d_in[2];
  const int*  dst = (const int*)d_in[3];
  const void* W1  = d_in[4];
  const void* W2  = d_in[5];
  const void* W3  = d_in[6];

  char* w = (char*)d_ws;                      // footprint: 7,819,264 bytes
  int* flag     = (int*)(w);                  // 4 B (4 KB reserved)
  int* deg      = (int*)(w + 4096);
  int* row_ptr  = (int*)(w + 49152);
  int* cursor   = (int*)(w + 94208);
  int* csr_src  = (int*)(w + 139264);         // ends 2,699,264
  int* csr_eid  = (int*)(w + 2699264);        // ends 5,259,264
  unsigned* eagg = (unsigned*)(w + 5259264);  // ends 7,819,264
  unsigned* Abuf = (unsigned*)(w + 2699264);  // aliases csr_eid (dead after k_edge_agg)

  const long WOFF1 = 8192;  // layer-1 weight offset in row-PAIR units (128*128/2)

  k_detect<<<1, 64, 0, stream>>>((const unsigned short*)W1, flag);
  k_zero<<<40, 256, 0, stream>>>(deg, NN);
  k_hist<<<2500, 256, 0, stream>>>(dst, deg);
  k_scan<<<1, 1024, 0, stream>>>(deg, row_ptr, cursor);
  k_scatter<<<2500, 256, 0, stream>>>(src, dst, cursor, csr_src, csr_eid);
  k_edge_agg<<<2500, 256, 0, stream>>>(ef, row_ptr, csr_eid, eagg, flag);

  // layer 0: h = node_feats -> d_out
  k_agg_h<<<2500, 256, 0, stream>>>(nf, 1, row_ptr, csr_src, eagg, deg, Abuf, flag);
  k_iso_pre<<<2500, 256, 0, stream>>>(nf, 1, W3, 0L, deg, Abuf, flag);
  k_lin<<<2500, 256, 0, stream>>>(Abuf, nf, 1, W1, W2, 0L, d_out, flag);
  k_iso_post<<<2500, 256, 0, stream>>>(Abuf, deg, d_out, flag);

  // layer 1: h = d_out -> d_out
  k_agg_h<<<2500, 256, 0, stream>>>(d_out, 1, row_ptr, csr_src, eagg, deg, Abuf, flag);
  k_iso_pre<<<2500, 256, 0, stream>>>(d_out, 1, W3, WOFF1, deg, Abuf, flag);
  k_lin<<<2500, 256, 0, stream>>>(Abuf, d_out, 1, W1, W2, WOFF1, d_out, flag);
  k_iso_post<<<2500, 256, 0, stream>>>(Abuf, deg, d_out, flag);
}

// Round 4
// 680.802 us; speedup vs baseline: 1.4190x; 1.4190x over previous
//
#include <hip/hip_runtime.h>

#define NN 10000
#define NE 640000
#define SLOPE 0.22916666666666666f

__device__ __forceinline__ float blo(unsigned v){ return __uint_as_float(v << 16); }
__device__ __forceinline__ float bhi(unsigned v){ return __uint_as_float(v & 0xffff0000u); }
__device__ __forceinline__ unsigned f2b(float x){
  unsigned u = __float_as_uint(x);
  return (u + 0x7fffu + ((u >> 16) & 1u)) >> 16;
}
__device__ __forceinline__ unsigned pack2(float a, float b){
  return f2b(a) | (f2b(b) << 16);
}
__device__ __forceinline__ float rrelu(float x){ return x >= 0.f ? x : x * SLOPE; }
__device__ __forceinline__ int clampi(int x, int hi){ return x < 0 ? 0 : (x > hi ? hi : x); }

// load/store feature PAIR (2j, 2j+1) of a 128-wide row; i = row*64 + j
__device__ __forceinline__ float2 ld2(const void* p, long i, int f32){
  if (f32) return ((const float2*)p)[i];
  unsigned v = ((const unsigned*)p)[i];
  return make_float2(blo(v), bhi(v));
}
__device__ __forceinline__ void st2(void* p, long i, float2 v, int f32){
  if (f32) ((float2*)p)[i] = v;
  else ((unsigned*)p)[i] = pack2(v.x, v.y);
}

// dtype sniffer (1 wave): bf16 normals -> exponent field in [100,135]; f32
// low-half u16s have ~uniform exponent fields (~57% pass). Threshold 450/512.
__global__ void k_detect(const unsigned short* __restrict__ w1, int* __restrict__ flag){
  int lane = threadIdx.x & 63;
  int pass = 0;
  for (int i = lane; i < 512; i += 64){
    unsigned short u = w1[i];
    int e = (u >> 7) & 0xFF;
    if ((u & 0x7FFF) == 0 || (e >= 100 && e <= 135)) pass++;
  }
  #pragma unroll
  for (int off = 32; off > 0; off >>= 1) pass += __shfl_down(pass, off);
  if (lane == 0) *flag = (pass < 450) ? 1 : 0;   // 1 => float32 inputs
}

__global__ void k_zero(int* __restrict__ p, int n){
  int i = blockIdx.x * blockDim.x + threadIdx.x;
  if (i < n) p[i] = 0;
}

// packed-bf16 copy of node_feats (both dtype modes)
__global__ void k_cast(const void* __restrict__ nf, unsigned* __restrict__ dst,
                       const int* __restrict__ flag){
  int f32 = *flag;
  int i = blockIdx.x * blockDim.x + threadIdx.x;   // 640000 pairs
  if (i >= NN * 64) return;
  float2 v = ld2(nf, i, f32);
  dst[i] = pack2(v.x, v.y);
}

__global__ void k_hist(const int* __restrict__ dst, int* __restrict__ deg){
  int e = blockIdx.x * blockDim.x + threadIdx.x;
  if (e < NE) atomicAdd(&deg[clampi(dst[e], NN - 1)], 1);
}

__global__ __launch_bounds__(1024) void k_scan(const int* __restrict__ deg,
                                               int* __restrict__ row_ptr,
                                               int* __restrict__ cursor){
  __shared__ int part[1024];
  int t = threadIdx.x;
  int base = t * 10;
  int local[10];
  int s = 0;
  #pragma unroll
  for (int j = 0; j < 10; j++){
    int idx = base + j;
    int v = (idx < NN) ? deg[idx] : 0;
    local[j] = s; s += v;
  }
  part[t] = s;
  __syncthreads();
  for (int off = 1; off < 1024; off <<= 1){
    int v = (t >= off) ? part[t - off] : 0;
    __syncthreads();
    part[t] += v;
    __syncthreads();
  }
  int pre = (t == 0) ? 0 : part[t - 1];
  #pragma unroll
  for (int j = 0; j < 10; j++){
    int idx = base + j;
    if (idx < NN){ int rp = pre + local[j]; row_ptr[idx] = rp; cursor[idx] = rp; }
  }
  if (t == 1023) row_ptr[NN] = part[1023];
}

__global__ void k_scatter(const int* __restrict__ src, const int* __restrict__ dst,
                          int* __restrict__ cursor,
                          int* __restrict__ csr_src, int* __restrict__ csr_eid){
  int e = blockIdx.x * blockDim.x + threadIdx.x;
  if (e >= NE) return;
  int d = clampi(dst[e], NN - 1);
  int p = clampi(atomicAdd(&cursor[d], 1), NE - 1);
  csr_src[p] = clampi(src[e], NN - 1);
  csr_eid[p] = e;
}

// eagg[n] = sum of edge_feats over edges into n (bf16 pairs out, f32 accum)
__global__ __launch_bounds__(256) void k_edge_agg(const void* __restrict__ ef,
                                                  const int* __restrict__ row_ptr,
                                                  const int* __restrict__ csr_eid,
                                                  unsigned* __restrict__ eagg,
                                                  const int* __restrict__ flag){
  int f32 = *flag;
  int wave = threadIdx.x >> 6, lane = threadIdx.x & 63;
  int n = blockIdx.x * 4 + wave;
  if (n >= NN) return;
  int beg = row_ptr[n], end = row_ptr[n + 1];
  float a0 = 0.f, a1 = 0.f;
  int i = beg;
  for (; i + 4 <= end; i += 4){
    int e0 = clampi(csr_eid[i],   NE - 1), e1 = clampi(csr_eid[i+1], NE - 1);
    int e2 = clampi(csr_eid[i+2], NE - 1), e3 = clampi(csr_eid[i+3], NE - 1);
    float2 v0 = ld2(ef, (long)e0 * 64 + lane, f32);
    float2 v1 = ld2(ef, (long)e1 * 64 + lane, f32);
    float2 v2 = ld2(ef, (long)e2 * 64 + lane, f32);
    float2 v3 = ld2(ef, (long)e3 * 64 + lane, f32);
    a0 += v0.x + v1.x + v2.x + v3.x;
    a1 += v0.y + v1.y + v2.y + v3.y;
  }
  for (; i < end; ++i){
    float2 v = ld2(ef, (long)clampi(csr_eid[i], NE - 1) * 64 + lane, f32);
    a0 += v.x; a1 += v.y;
  }
  eagg[n * 64 + lane] = pack2(a0, a1);
}

// A[n] = (eagg[n] + sum h[src]) / max(deg,1) ; h is ALWAYS packed bf16 here
__global__ __launch_bounds__(256) void k_agg_h(const unsigned* __restrict__ h,
                                               const int* __restrict__ row_ptr,
                                               const int* __restrict__ csr_src,
                                               const unsigned* __restrict__ eagg,
                                               const int* __restrict__ deg,
                                               unsigned* __restrict__ A){
  int wave = threadIdx.x >> 6, lane = threadIdx.x & 63;
  int n = blockIdx.x * 4 + wave;
  if (n >= NN) return;
  int beg = row_ptr[n], end = row_ptr[n + 1];
  unsigned ev = eagg[n * 64 + lane];
  float a0 = blo(ev), a1 = bhi(ev);
  int i = beg;
  for (; i + 4 <= end; i += 4){
    int s0 = clampi(csr_src[i],   NN - 1), s1 = clampi(csr_src[i+1], NN - 1);
    int s2 = clampi(csr_src[i+2], NN - 1), s3 = clampi(csr_src[i+3], NN - 1);
    unsigned v0 = h[s0 * 64 + lane], v1 = h[s1 * 64 + lane];
    unsigned v2 = h[s2 * 64 + lane], v3 = h[s3 * 64 + lane];
    a0 += blo(v0) + blo(v1) + blo(v2) + blo(v3);
    a1 += bhi(v0) + bhi(v1) + bhi(v2) + bhi(v3);
  }
  for (; i < end; ++i){
    unsigned v = h[clampi(csr_src[i], NN - 1) * 64 + lane];
    a0 += blo(v); a1 += bhi(v);
  }
  float inv = 1.f / fmaxf((float)deg[n], 1.f);
  A[n * 64 + lane] = pack2(a0 * inv, a1 * inv);
}

// out[n] = rrelu(A[n]@W1 + H[n]@Wself), Wself = (deg? W2 : W3).
// W1||W2 staged in LDS as f32 pairs (128 KB); 8 waves/block, 5 nodes/wave.
// A==0 for iso nodes, so their result is rrelu(H@W3) — recomputed from global
// W3 in a (essentially never taken) wave-uniform fallback.
// outmode: 0 -> packed bf16, 1 -> harness dtype (per flag).
__global__ __launch_bounds__(512) void k_lin(const unsigned* __restrict__ A,
                                             const unsigned* __restrict__ H,
                                             const void* __restrict__ W1,
                                             const void* __restrict__ W2,
                                             const void* __restrict__ W3, long woff,
                                             const int* __restrict__ deg,
                                             void* __restrict__ out, int outmode,
                                             const int* __restrict__ flag){
  int f32 = *flag;
  __shared__ float2 lw[16384];                  // [0,8192)=W1 pairs, [8192,16384)=W2
  int t = threadIdx.x;
  for (int i = t; i < 16384; i += 512){
    lw[i] = (i < 8192) ? ld2(W1, woff + i, f32) : ld2(W2, woff + (i - 8192), f32);
  }
  __syncthreads();
  int wave = t >> 6, lane = t & 63;
  int nb = (blockIdx.x * 8 + wave) * 5;         // 250 blocks * 8 waves * 5 = 10000
  long base[5]; int valid[5];
  float a0[5], a1[5];
  #pragma unroll
  for (int j = 0; j < 5; ++j){
    int n = nb + j;
    valid[j] = (n < NN);
    base[j] = valid[j] ? (long)n * 64 : 0;
    a0[j] = 0.f; a1[j] = 0.f;
  }
  for (int kk = 0; kk < 64; ++kk){
    float2 w1a = lw[(2 * kk) * 64 + lane];
    float2 w1b = lw[(2 * kk + 1) * 64 + lane];
    float2 w2a = lw[8192 + (2 * kk) * 64 + lane];
    float2 w2b = lw[8192 + (2 * kk + 1) * 64 + lane];
    #pragma unroll
    for (int j = 0; j < 5; ++j){
      unsigned av = A[base[j] + kk];
      unsigned hv = H[base[j] + kk];
      float A0 = blo(av), A1 = bhi(av);
      float H0 = blo(hv), H1 = bhi(hv);
      a0[j] += A0 * w1a.x + A1 * w1b.x + H0 * w2a.x + H1 * w2b.x;
      a1[j] += A0 * w1a.y + A1 * w1b.y + H0 * w2a.y + H1 * w2b.y;
    }
  }
  // iso fallback (deg==0): overwrite with H @ W3 (global reads; ~never taken)
  #pragma unroll
  for (int j = 0; j < 5; ++j){
    if (valid[j] && deg[nb + j] == 0){
      float b0 = 0.f, b1 = 0.f;
      for (int kk = 0; kk < 64; ++kk){
        unsigned hv = H[base[j] + kk];
        float H0 = blo(hv), H1 = bhi(hv);
        float2 wa = ld2(W3, woff + (long)(2 * kk) * 64 + lane, f32);
        float2 wb = ld2(W3, woff + (long)(2 * kk + 1) * 64 + lane, f32);
        b0 += H0 * wa.x + H1 * wb.x;
        b1 += H0 * wa.y + H1 * wb.y;
      }
      a0[j] = b0; a1[j] = b1;
    }
  }
  #pragma unroll
  for (int j = 0; j < 5; ++j){
    if (!valid[j]) continue;
    float r0 = rrelu(a0[j]), r1 = rrelu(a1[j]);
    if (outmode) st2(out, base[j] + lane, make_float2(r0, r1), f32);
    else ((unsigned*)out)[base[j] + lane] = pack2(r0, r1);
  }
}

extern "C" void kernel_launch(void* const* d_in, const int* in_sizes, int n_in,
                              void* d_out, int out_size, void* d_ws, size_t ws_size,
                              hipStream_t stream) {
  const void* nf  = d_in[0];
  const void* ef  = d_in[1];
  const int*  src = (const int*)d_in[2];
  const int*  dst = (const int*)d_in[3];
  const void* W1  = d_in[4];
  const void* W2  = d_in[5];
  const void* W3  = d_in[6];

  char* w = (char*)d_ws;                       // footprint: ~15.5 MB
  int* flag      = (int*)(w);                  // 4 B (4 KB reserved)
  int* deg       = (int*)(w + 4096);
  int* row_ptr   = (int*)(w + 49152);
  int* cursor    = (int*)(w + 94208);
  int* csr_src   = (int*)(w + 139264);         // ends  2,699,264
  int* csr_eid   = (int*)(w + 2699264);        // ends  5,259,264
  unsigned* eagg = (unsigned*)(w + 5259264);   // ends  7,819,264
  unsigned* Abuf = (unsigned*)(w + 7819264);   // ends 10,379,264
  unsigned* nfbf = (unsigned*)(w + 10379264);  // ends 12,939,264
  unsigned* h1   = (unsigned*)(w + 12939264);  // ends 15,499,264

  const long WOFF1 = 8192;  // layer-1 weight offset in row-PAIR units

  k_detect<<<1, 64, 0, stream>>>((const unsigned short*)W1, flag);
  k_zero<<<40, 256, 0, stream>>>(deg, NN);
  k_cast<<<2500, 256, 0, stream>>>(nf, nfbf, flag);
  k_hist<<<2500, 256, 0, stream>>>(dst, deg);
  k_scan<<<1, 1024, 0, stream>>>(deg, row_ptr, cursor);
  k_scatter<<<2500, 256, 0, stream>>>(src, dst, cursor, csr_src, csr_eid);
  k_edge_agg<<<2500, 256, 0, stream>>>(ef, row_ptr, csr_eid, eagg, flag);

  // layer 0: h = nfbf -> h1 (bf16)
  k_agg_h<<<2500, 256, 0, stream>>>(nfbf, row_ptr, csr_src, eagg, deg, Abuf);
  k_lin<<<250, 512, 0, stream>>>(Abuf, nfbf, W1, W2, W3, 0L, deg, h1, 0, flag);

  // layer 1: h = h1 -> d_out (harness dtype)
  k_agg_h<<<2500, 256, 0, stream>>>(h1, row_ptr, csr_src, eagg, deg, Abuf);
  k_lin<<<250, 512, 0, stream>>>(Abuf, h1, W1, W2, W3, WOFF1, deg, d_out, 1, flag);
}

// Round 5
// 645.743 us; speedup vs baseline: 1.4960x; 1.0543x over previous
//
#include <hip/hip_runtime.h>

#define NN 10000
#define NE 640000
#define SLOPE 0.22916666666666666f

typedef float __attribute__((ext_vector_type(2))) f2v;

__device__ __forceinline__ float blo(unsigned v){ return __uint_as_float(v << 16); }
__device__ __forceinline__ float bhi(unsigned v){ return __uint_as_float(v & 0xffff0000u); }
__device__ __forceinline__ unsigned f2b(float x){
  unsigned u = __float_as_uint(x);
  return (u + 0x7fffu + ((u >> 16) & 1u)) >> 16;
}
__device__ __forceinline__ unsigned pack2(float a, float b){
  return f2b(a) | (f2b(b) << 16);
}
__device__ __forceinline__ float rrelu(float x){ return x >= 0.f ? x : x * SLOPE; }
__device__ __forceinline__ int clampi(int x, int hi){ return x < 0 ? 0 : (x > hi ? hi : x); }

// load feature PAIR (2j, 2j+1) of a 128-wide row; i = row*64 + j
__device__ __forceinline__ float2 ld2(const void* p, long i, int f32){
  if (f32) return ((const float2*)p)[i];
  unsigned v = ((const unsigned*)p)[i];
  return make_float2(blo(v), bhi(v));
}
// nontemporal variant (single-use streams: edge_feats)
__device__ __forceinline__ float2 ldnt(const void* p, long i, int f32){
  if (f32){ f2v v = __builtin_nontemporal_load(((const f2v*)p) + i);
            return make_float2(v.x, v.y); }
  unsigned v = __builtin_nontemporal_load(((const unsigned*)p) + i);
  return make_float2(blo(v), bhi(v));
}
__device__ __forceinline__ void st2(void* p, long i, float2 v, int f32){
  if (f32) ((float2*)p)[i] = v;
  else ((unsigned*)p)[i] = pack2(v.x, v.y);
}

// detect input dtype (block 0, wave 0) + zero deg. bf16 normals -> exp field
// in [100,135] for ~every u16; f32 low-half u16s ~uniform (~57% pass).
__global__ void k_init(const unsigned short* __restrict__ w1,
                       int* __restrict__ flag, int* __restrict__ deg){
  int i = blockIdx.x * 256 + threadIdx.x;
  if (i < NN) deg[i] = 0;
  if (blockIdx.x == 0 && threadIdx.x < 64){
    int lane = threadIdx.x;
    int pass = 0;
    for (int k = lane; k < 512; k += 64){
      unsigned short u = w1[k];
      int e = (u >> 7) & 0xFF;
      if ((u & 0x7FFF) == 0 || (e >= 100 && e <= 135)) pass++;
    }
    #pragma unroll
    for (int off = 32; off > 0; off >>= 1) pass += __shfl_down(pass, off);
    if (lane == 0) *flag = (pass < 450) ? 1 : 0;   // 1 => float32 inputs
  }
}

// fused: packed-bf16 cast of node_feats + in-degree histogram (same 640k grid)
__global__ void k_cast_hist(const void* __restrict__ nf, unsigned* __restrict__ nfbf,
                            const int* __restrict__ dst, int* __restrict__ deg,
                            const int* __restrict__ flag){
  int f32 = *flag;
  int i = blockIdx.x * 256 + threadIdx.x;      // 0..640000
  if (i < NN * 64){
    float2 v = ld2(nf, i, f32);
    nfbf[i] = pack2(v.x, v.y);
  }
  if (i < NE) atomicAdd(&deg[clampi(dst[i], NN - 1)], 1);
}

__global__ __launch_bounds__(1024) void k_scan(const int* __restrict__ deg,
                                               int* __restrict__ row_ptr,
                                               int* __restrict__ cursor){
  __shared__ int part[1024];
  int t = threadIdx.x;
  int base = t * 10;
  int local[10];
  int s = 0;
  #pragma unroll
  for (int j = 0; j < 10; j++){
    int idx = base + j;
    int v = (idx < NN) ? deg[idx] : 0;
    local[j] = s; s += v;
  }
  part[t] = s;
  __syncthreads();
  for (int off = 1; off < 1024; off <<= 1){
    int v = (t >= off) ? part[t - off] : 0;
    __syncthreads();
    part[t] += v;
    __syncthreads();
  }
  int pre = (t == 0) ? 0 : part[t - 1];
  #pragma unroll
  for (int j = 0; j < 10; j++){
    int idx = base + j;
    if (idx < NN){ int rp = pre + local[j]; row_ptr[idx] = rp; cursor[idx] = rp; }
  }
  if (t == 1023) row_ptr[NN] = part[1023];
}

// packed CSR entry: (eid << 32) | src  — one 8 B scattered store per edge
__global__ void k_scatter(const int* __restrict__ src, const int* __restrict__ dst,
                          int* __restrict__ cursor,
                          unsigned long long* __restrict__ csr){
  int e = blockIdx.x * 256 + threadIdx.x;
  if (e >= NE) return;
  int d = clampi(dst[e], NN - 1);
  int p = clampi(atomicAdd(&cursor[d], 1), NE - 1);
  csr[p] = ((unsigned long long)(unsigned)e << 32) | (unsigned)clampi(src[e], NN - 1);
}

// fused layer-0 aggregation: one CSR walk yields BOTH
//   eagg[n] = sum ef[e]          (bf16, reused by layer 1)
//   A[n]    = (eagg + sum nfbf[src]) / max(deg,1)   (bf16)
__global__ __launch_bounds__(256) void k_agg0(const void* __restrict__ ef,
                                              const unsigned* __restrict__ nfbf,
                                              const int* __restrict__ row_ptr,
                                              const unsigned long long* __restrict__ csr,
                                              unsigned* __restrict__ eagg,
                                              unsigned* __restrict__ A,
                                              const int* __restrict__ flag){
  int f32 = *flag;
  int wave = threadIdx.x >> 6, lane = threadIdx.x & 63;
  int n = blockIdx.x * 4 + wave;
  if (n >= NN) return;
  int beg = row_ptr[n], end = row_ptr[n + 1];
  float e0 = 0.f, e1 = 0.f, h0 = 0.f, h1 = 0.f;
  int i = beg;
  for (; i + 4 <= end; i += 4){
    unsigned long long c0 = csr[i],   c1 = csr[i+1];
    unsigned long long c2 = csr[i+2], c3 = csr[i+3];
    float2 va = ldnt(ef, (long)(c0 >> 32) * 64 + lane, f32);
    float2 vb = ldnt(ef, (long)(c1 >> 32) * 64 + lane, f32);
    float2 vc = ldnt(ef, (long)(c2 >> 32) * 64 + lane, f32);
    float2 vd = ldnt(ef, (long)(c3 >> 32) * 64 + lane, f32);
    unsigned ha = nfbf[(unsigned)(c0 & 0xffffffffu) * 64 + lane];
    unsigned hb = nfbf[(unsigned)(c1 & 0xffffffffu) * 64 + lane];
    unsigned hc = nfbf[(unsigned)(c2 & 0xffffffffu) * 64 + lane];
    unsigned hd = nfbf[(unsigned)(c3 & 0xffffffffu) * 64 + lane];
    e0 += va.x + vb.x + vc.x + vd.x;
    e1 += va.y + vb.y + vc.y + vd.y;
    h0 += blo(ha) + blo(hb) + blo(hc) + blo(hd);
    h1 += bhi(ha) + bhi(hb) + bhi(hc) + bhi(hd);
  }
  for (; i < end; ++i){
    unsigned long long c = csr[i];
    float2 v = ldnt(ef, (long)(c >> 32) * 64 + lane, f32);
    unsigned hv = nfbf[(unsigned)(c & 0xffffffffu) * 64 + lane];
    e0 += v.x; e1 += v.y;
    h0 += blo(hv); h1 += bhi(hv);
  }
  float inv = 1.f / fmaxf((float)(end - beg), 1.f);
  eagg[n * 64 + lane] = pack2(e0, e1);
  A[n * 64 + lane] = pack2((e0 + h0) * inv, (e1 + h1) * inv);
}

// layer-1 aggregation: A[n] = (eagg[n] + sum h1[src]) / max(deg,1)
__global__ __launch_bounds__(256) void k_agg_h(const unsigned* __restrict__ h,
                                               const int* __restrict__ row_ptr,
                                               const unsigned long long* __restrict__ csr,
                                               const unsigned* __restrict__ eagg,
                                               unsigned* __restrict__ A){
  int wave = threadIdx.x >> 6, lane = threadIdx.x & 63;
  int n = blockIdx.x * 4 + wave;
  if (n >= NN) return;
  int beg = row_ptr[n], end = row_ptr[n + 1];
  unsigned ev = eagg[n * 64 + lane];
  float a0 = blo(ev), a1 = bhi(ev);
  int i = beg;
  for (; i + 4 <= end; i += 4){
    unsigned s0 = (unsigned)(csr[i]   & 0xffffffffu);
    unsigned s1 = (unsigned)(csr[i+1] & 0xffffffffu);
    unsigned s2 = (unsigned)(csr[i+2] & 0xffffffffu);
    unsigned s3 = (unsigned)(csr[i+3] & 0xffffffffu);
    unsigned v0 = h[s0 * 64 + lane], v1 = h[s1 * 64 + lane];
    unsigned v2 = h[s2 * 64 + lane], v3 = h[s3 * 64 + lane];
    a0 += blo(v0) + blo(v1) + blo(v2) + blo(v3);
    a1 += bhi(v0) + bhi(v1) + bhi(v2) + bhi(v3);
  }
  for (; i < end; ++i){
    unsigned v = h[(unsigned)(csr[i] & 0xffffffffu) * 64 + lane];
    a0 += blo(v); a1 += bhi(v);
  }
  float inv = 1.f / fmaxf((float)(end - beg), 1.f);
  A[n * 64 + lane] = pack2(a0 * inv, a1 * inv);
}

// out[n] = rrelu(A[n]@W1 + H[n]@W2), iso (deg==0) -> rrelu(H@W3).
// W1||W2 staged in LDS as packed bf16 (64 KB); 8 waves/block, 5 nodes/wave.
// outmode: 0 -> packed bf16, 1 -> harness dtype (per flag).
__global__ __launch_bounds__(512) void k_lin(const unsigned* __restrict__ A,
                                             const unsigned* __restrict__ H,
                                             const void* __restrict__ W1,
                                             const void* __restrict__ W2,
                                             const void* __restrict__ W3, long woff,
                                             const int* __restrict__ deg,
                                             void* __restrict__ out, int outmode,
                                             const int* __restrict__ flag){
  int f32 = *flag;
  __shared__ unsigned lw[16384];            // [0,8192)=W1 pairs, [8192,16384)=W2
  int t = threadIdx.x;
  for (int i = t; i < 16384; i += 512){
    float2 v = (i < 8192) ? ld2(W1, woff + i, f32) : ld2(W2, woff + (i - 8192), f32);
    lw[i] = pack2(v.x, v.y);
  }
  __syncthreads();
  int wave = t >> 6, lane = t & 63;
  int nb = (blockIdx.x * 8 + wave) * 5;     // 250 blocks * 8 waves * 5 = 10000
  long base[5]; int valid[5];
  float a0[5], a1[5];
  #pragma unroll
  for (int j = 0; j < 5; ++j){
    int n = nb + j;
    valid[j] = (n < NN);
    base[j] = valid[j] ? (long)n * 64 : 0;
    a0[j] = 0.f; a1[j] = 0.f;
  }
  for (int kk = 0; kk < 64; ++kk){
    unsigned w1a = lw[(2 * kk) * 64 + lane];
    unsigned w1b = lw[(2 * kk + 1) * 64 + lane];
    unsigned w2a = lw[8192 + (2 * kk) * 64 + lane];
    unsigned w2b = lw[8192 + (2 * kk + 1) * 64 + lane];
    #pragma unroll
    for (int j = 0; j < 5; ++j){
      unsigned av = A[base[j] + kk];
      unsigned hv = H[base[j] + kk];
      float A0 = blo(av), A1 = bhi(av);
      float H0 = blo(hv), H1 = bhi(hv);
      a0[j] += A0 * blo(w1a) + A1 * blo(w1b) + H0 * blo(w2a) + H1 * blo(w2b);
      a1[j] += A0 * bhi(w1a) + A1 * bhi(w1b) + H0 * bhi(w2a) + H1 * bhi(w2b);
    }
  }
  // iso fallback (deg==0): overwrite with H @ W3 (global reads; ~never taken)
  #pragma unroll
  for (int j = 0; j < 5; ++j){
    if (valid[j] && deg[nb + j] == 0){
      float b0 = 0.f, b1 = 0.f;
      for (int kk = 0; kk < 64; ++kk){
        unsigned hv = H[base[j] + kk];
        float H0 = blo(hv), H1 = bhi(hv);
        float2 wa = ld2(W3, woff + (long)(2 * kk) * 64 + lane, f32);
        float2 wb = ld2(W3, woff + (long)(2 * kk + 1) * 64 + lane, f32);
        b0 += H0 * wa.x + H1 * wb.x;
        b1 += H0 * wa.y + H1 * wb.y;
      }
      a0[j] = b0; a1[j] = b1;
    }
  }
  #pragma unroll
  for (int j = 0; j < 5; ++j){
    if (!valid[j]) continue;
    float r0 = rrelu(a0[j]), r1 = rrelu(a1[j]);
    if (outmode) st2(out, base[j] + lane, make_float2(r0, r1), f32);
    else ((unsigned*)out)[base[j] + lane] = pack2(r0, r1);
  }
}

extern "C" void kernel_launch(void* const* d_in, const int* in_sizes, int n_in,
                              void* d_out, int out_size, void* d_ws, size_t ws_size,
                              hipStream_t stream) {
  const void* nf  = d_in[0];
  const void* ef  = d_in[1];
  const int*  src = (const int*)d_in[2];
  const int*  dst = (const int*)d_in[3];
  const void* W1  = d_in[4];
  const void* W2  = d_in[5];
  const void* W3  = d_in[6];

  char* w = (char*)d_ws;                        // footprint: 15,499,264 B
  int* flag     = (int*)(w);                    // 4 B   (4 KB reserved)
  int* deg      = (int*)(w + 4096);             // 40 KB
  int* row_ptr  = (int*)(w + 49152);            // 40 KB + 4
  int* cursor   = (int*)(w + 94208);            // 40 KB
  unsigned long long* csr = (unsigned long long*)(w + 139264);  // 5.12 MB -> 5,259,264
  unsigned* eagg = (unsigned*)(w + 5259264);    // 2.56 MB -> 7,819,264
  unsigned* Abuf = (unsigned*)(w + 7819264);    // 2.56 MB -> 10,379,264
  unsigned* nfbf = (unsigned*)(w + 10379264);   // 2.56 MB -> 12,939,264
  unsigned* h1   = (unsigned*)(w + 12939264);   // 2.56 MB -> 15,499,264

  const long WOFF1 = 8192;  // layer-1 weight offset in row-PAIR units

  k_init<<<40, 256, 0, stream>>>((const unsigned short*)W1, flag, deg);
  k_cast_hist<<<2500, 256, 0, stream>>>(nf, nfbf, dst, deg, flag);
  k_scan<<<1, 1024, 0, stream>>>(deg, row_ptr, cursor);
  k_scatter<<<2500, 256, 0, stream>>>(src, dst, cursor, csr);
  k_agg0<<<2500, 256, 0, stream>>>(ef, nfbf, row_ptr, csr, eagg, Abuf, flag);

  // layer 0 GEMM: -> h1 (bf16)
  k_lin<<<250, 512, 0, stream>>>(Abuf, nfbf, W1, W2, W3, 0L, deg, h1, 0, flag);

  // layer 1: aggregate h1, GEMM -> d_out (harness dtype)
  k_agg_h<<<2500, 256, 0, stream>>>(h1, row_ptr, csr, eagg, Abuf);
  k_lin<<<250, 512, 0, stream>>>(Abuf, h1, W1, W2, W3, WOFF1, deg, d_out, 1, flag);
}